// Round 16
// baseline (413.886 us; speedup 1.0000x reference)
//
#include <hip/hip_runtime.h>

#define TT     32
#define HW     4096           // 64*64
#define LROW   68             // 66 cols + 2 pad -> rows 16B-aligned (b128 reads)
#define LPLANE (6 * LROW)     // 6 halo rows per cin = 408
#define SXSZ   (3 * LPLANE)   // 1224 floats per plane buffer
#define NSTG   (3 * 6 * 66)   // 1188 staged elements per plane

typedef float f32x2 __attribute__((ext_vector_type(2)));

__device__ __forceinline__ float fsigmoid(float x) {
    return __builtin_amdgcn_rcpf(1.0f + __builtin_amdgcn_exp2f(x * -1.4426950408889634f));
}
__device__ __forceinline__ float ftanh(float x) {
    return 2.0f * __builtin_amdgcn_rcpf(1.0f + __builtin_amdgcn_exp2f(x * -2.8853900817779268f)) - 1.0f;
}
// force a wave-uniform float into an SGPR
__device__ __forceinline__ float sgprf(float v) {
    return __uint_as_float(__builtin_amdgcn_readfirstlane(__float_as_uint(v)));
}
__device__ __forceinline__ f32x2 s2(float v) { return (f32x2){v, v}; }

// Round-6 base (best verified: 306us counter; VGPR 64 -> 8-wave tier) with
// the conv on PACKED fp32 pairs: <2 x float> fma lowers to v_pk_fma_f32 on
// gfx950, halving conv VALU instrs 216 -> 108 per thread-t. Register count
// neutral; occupancy tier preserved.
__global__ __launch_bounds__(256, 2) void convqrnn(
    const float* __restrict__ X,    // (4,3,32,64,64)
    const float* __restrict__ Wc,   // (256,3,2,3,3)
    const float* __restrict__ bc,   // (256)
    const float* __restrict__ Wci,  // (64,64,64)
    const float* __restrict__ Wcf,
    const float* __restrict__ Wco,
    float* __restrict__ out)        // (4,64,32,64,64)
{
    __shared__ float sx[2 * SXSZ];     // double-buffered staged plane
    __shared__ float gb[2 * 2048];     // double-buffered gate exchange, 2 couts
    __shared__ float wl[576];          // weights: (g*9+ci*3+kh)*16 + which*3 + kw

    const int tid = threadIdx.x;
    const int h0  = blockIdx.x * 4;    // 16 row-tiles of height 4, full width
    const int co0 = blockIdx.y * 2;    // this block handles couts {co0, co0+1}
    const int b   = blockIdx.z;

    // gate-compute mapping: wave g handles gate g; lane owns 4 consecutive cols
    const int g  = tid >> 6;
    const int l  = tid & 63;
    const int r  = l >> 4;            // 0..3 tile row
    const int c0 = (l & 15) * 4;      // col base (0,4,...,60)

    // recurrence-owner mapping: pixel p = tid (4 rows x 64 cols, row-major)
    const int prow = tid >> 6;
    const int pcol = tid & 63;
    const int opix = (h0 + prow) * 64 + pcol;

    const float wciA = Wci[co0 * HW + opix];
    const float wcfA = Wcf[co0 * HW + opix];
    const float wcoA = Wco[co0 * HW + opix];
    const float wciB = Wci[(co0 + 1) * HW + opix];
    const float wcfB = Wcf[(co0 + 1) * HW + opix];
    const float wcoB = Wco[(co0 + 1) * HW + opix];

    // ---- cooperative fill of the LDS weight table (432 elems, strided) ----
    // slot: wl[(g2*9 + ci*3 + kh)*16 + which*3 + kw]
    //   which: 0=(A,dt0) 1=(A,dt1) 2=(B,dt0) 3=(B,dt1)
    for (int fi = tid; fi < 432; fi += 256) {
        int grp   = fi / 12;
        int e     = fi - grp * 12;
        int g2    = grp / 9;
        int ck    = grp - g2 * 9;
        int ci    = ck / 3;
        int kh    = ck - ci * 3;
        int which = e / 3;
        int kw    = e - which * 3;
        int cs    = which >> 1;
        int dt    = which & 1;
        wl[grp * 16 + e] =
            Wc[(size_t)(g2 * 64 + co0 + cs) * 54 + ci * 18 + dt * 9 + kh * 3 + kw];
    }
    const float bgA = sgprf(bc[g * 64 + co0]);
    const float bgB = sgprf(bc[g * 64 + co0 + 1]);

    // ---- staging precompute: 5 chunks of 256 covering 3x6x66 halo tile ----
    const float* __restrict__ Xb = X + (size_t)b * (3 * TT * HW);
    int soff[5];
    int goff[5];
    int svmask = 0;
    #pragma unroll
    for (int k = 0; k < 5; ++k) {
        int idx  = tid + k * 256;
        bool inr = (idx < NSTG);
        int idc  = inr ? idx : 0;
        int ci   = idc / 396;              // 6*66
        int rem  = idc - ci * 396;
        int y    = rem / 66;
        int x    = rem - y * 66;
        int gh   = h0 + y - 1;
        int gw   = x - 1;
        bool v   = inr && (gh >= 0) && (gh < 64) && (gw >= 0) && (gw < 64);
        int ghc  = gh < 0 ? 0 : (gh > 63 ? 63 : gh);
        int gwc  = gw < 0 ? 0 : (gw > 63 ? 63 : gw);
        soff[k]  = inr ? (ci * LPLANE + y * LROW + x) : (LROW - 1); // dummy pad slot
        goff[k]  = ci * (TT * HW) + ghc * 64 + gwc;                 // plane 0
        svmask  |= (v ? 1 : 0) << k;
    }

    // prologue: stage plane t=0 into buffer 0
    #pragma unroll
    for (int k = 0; k < 5; ++k) {
        float v = ((svmask >> k) & 1) ? Xb[goff[k]] : 0.0f;
        sx[soff[k]] = v;
        goff[k] += HW;                       // -> plane 1
    }

    // output addressing (scalar base + 32-bit vector offset)
    float* __restrict__ outA = out + (size_t)(b * 64 + co0) * (TT * HW);
    float* __restrict__ outB = outA + (size_t)(TT * HW);
    int ooff = opix;

    // dt=0 partial carries (packed pairs), per cout
    f32x2 aA01 = {0.f, 0.f}, aA23 = {0.f, 0.f};
    f32x2 aB01 = {0.f, 0.f}, aB23 = {0.f, 0.f};
    float CA = 0.f, CB = 0.f;

    __syncthreads();   // plane 0 staged + weight table filled

    for (int t = 0; t < TT; ++t) {
        // never-taken uniform MayDef on wl: blocks LICM/GVN from hoisting the
        // (loop-invariant) weight loads into 108 registers. grid.x==16.
        if (blockIdx.x == 0xFFFFFFFFu) wl[tid] = 0.0f;

        const float* __restrict__ sxb = &sx[(t & 1) * SXSZ];
        float*       __restrict__ gbb = &gb[(t & 1) * 2048];

        // prefetch next plane's staging values (VMEM overlaps FMAs)
        float stv[5];
        if (t < TT - 1) {                    // uniform branch
            #pragma unroll
            for (int k = 0; k < 5; ++k) {
                stv[k] = ((svmask >> k) & 1) ? Xb[goff[k]] : 0.0f;
                goff[k] += HW;
            }
        }

        // conv on packed pairs: s* = dt=1 taps; n* = dt=0 taps (next step)
        f32x2 sA01 = s2(bgA), sA23 = s2(bgA);
        f32x2 sB01 = s2(bgB), sB23 = s2(bgB);
        f32x2 nA01 = {0.f, 0.f}, nA23 = {0.f, 0.f};
        f32x2 nB01 = {0.f, 0.f}, nB23 = {0.f, 0.f};
        #pragma unroll
        for (int ci = 0; ci < 3; ++ci)
            #pragma unroll
            for (int kh = 0; kh < 3; ++kh) {
                // window row: 6 floats (b128 + b64, 2-way banked = free)
                const float* rowp = &sxb[ci * LPLANE + (r + kh) * LROW + c0];
                float4 lo = *(const float4*)rowp;
                float2 hi = *(const float2*)(rowp + 4);
                const f32x2 w01 = {lo.x, lo.y};
                const f32x2 w23 = {lo.z, lo.w};
                const f32x2 w45 = {hi.x, hi.y};
                const f32x2 w12 = {lo.y, lo.z};
                const f32x2 w34 = {lo.w, hi.x};

                // weights: 3 uniform-address b128 broadcasts, direct indexing
                const int ws = (g * 9 + ci * 3 + kh) * 16;
                float4 qa = *(const float4*)&wl[ws];      // pA0 pA1 pA2 cA0
                float4 qb = *(const float4*)&wl[ws + 4];  // cA1 cA2 pB0 pB1
                float4 qc = *(const float4*)&wl[ws + 8];  // pB2 cB0 cB1 cB2

                // cout A, dt1 (s) and dt0 (n): 12 pk_fma
                sA01 += s2(qa.w) * w01;  sA23 += s2(qa.w) * w23;
                sA01 += s2(qb.x) * w12;  sA23 += s2(qb.x) * w34;
                sA01 += s2(qb.y) * w23;  sA23 += s2(qb.y) * w45;
                nA01 += s2(qa.x) * w01;  nA23 += s2(qa.x) * w23;
                nA01 += s2(qa.y) * w12;  nA23 += s2(qa.y) * w34;
                nA01 += s2(qa.z) * w23;  nA23 += s2(qa.z) * w45;

                // cout B: 12 pk_fma
                sB01 += s2(qc.y) * w01;  sB23 += s2(qc.y) * w23;
                sB01 += s2(qc.z) * w12;  sB23 += s2(qc.z) * w34;
                sB01 += s2(qc.w) * w23;  sB23 += s2(qc.w) * w45;
                nB01 += s2(qb.z) * w01;  nB23 += s2(qb.z) * w23;
                nB01 += s2(qb.w) * w12;  nB23 += s2(qb.w) * w34;
                nB01 += s2(qc.x) * w23;  nB23 += s2(qc.x) * w45;
            }

        const f32x2 gA01 = sA01 + aA01, gA23 = sA23 + aA23;
        const f32x2 gB01 = sB01 + aB01, gB23 = sB23 + aB23;
        aA01 = nA01; aA23 = nA23;
        aB01 = nB01; aB23 = nB23;
        *(float4*)&gbb[g * 256 + r * 64 + c0] =
            make_float4(gA01.x, gA01.y, gA23.x, gA23.y);
        *(float4*)&gbb[1024 + g * 256 + r * 64 + c0] =
            make_float4(gB01.x, gB01.y, gB23.x, gB23.y);

        // commit staged plane t+1 into the other buffer (before the barrier)
        if (t < TT - 1) {                    // uniform branch
            float* __restrict__ sxn = &sx[((t + 1) & 1) * SXSZ];
            #pragma unroll
            for (int k = 0; k < 5; ++k) sxn[soff[k]] = stv[k];
        }

        __syncthreads();   // gates(t) visible; plane t+1 committed

        // recurrence: owner thread per pixel, both couts
        {
            const float iv = gbb[tid];
            const float fv = gbb[256 + tid];
            const float gg = gbb[512 + tid];
            const float ov = gbb[768 + tid];
            const float ig = fsigmoid(iv + wciA * CA);
            const float fg = fsigmoid(fv + wcfA * CA);
            const float Cn = fg * CA + ig * ftanh(gg);
            const float og = fsigmoid(ov + wcoA * Cn);
            outA[ooff] = og * ftanh(Cn);
            CA = Cn;
        }
        {
            const float iv = gbb[1024 + tid];
            const float fv = gbb[1024 + 256 + tid];
            const float gg = gbb[1024 + 512 + tid];
            const float ov = gbb[1024 + 768 + tid];
            const float ig = fsigmoid(iv + wciB * CB);
            const float fg = fsigmoid(fv + wcfB * CB);
            const float Cn = fg * CB + ig * ftanh(gg);
            const float og = fsigmoid(ov + wcoB * Cn);
            outB[ooff] = og * ftanh(Cn);
            CB = Cn;
        }
        ooff += HW;
    }
}

extern "C" void kernel_launch(void* const* d_in, const int* in_sizes, int n_in,
                              void* d_out, int out_size, void* d_ws, size_t ws_size,
                              hipStream_t stream) {
    const float* X   = (const float*)d_in[0];
    const float* Wc  = (const float*)d_in[1];
    const float* bc  = (const float*)d_in[2];
    const float* Wci = (const float*)d_in[3];
    const float* Wcf = (const float*)d_in[4];
    const float* Wco = (const float*)d_in[5];
    float* out = (float*)d_out;

    dim3 grid(16, 32, 4);   // row-tiles, cout-pairs, batch
    convqrnn<<<grid, 256, 0, stream>>>(X, Wc, bc, Wci, Wcf, Wco, out);
}